// Round 6
// baseline (21653.470 us; speedup 1.0000x reference)
//
#include <hip/hip_runtime.h>
#include <stdint.h>

#define TT 12
#define NITERS 10
#define NCAND 1000
#define AD 6
#define BD 16
#define HD 200
#define ZD 30
#define NROWS 16000
#define NELEM 1152000u

// ws layout (float offsets). Total 5,337,552 floats = 21.35 MB.
#define OFF_WALL 0u           // [240][256] stacked [Wb;Ws;Wa] padded (rows 236..239 = 0)
#define OFF_BB   61440u       // [256]
#define OFF_WZT  61696u       // [32][200]  Wz transposed (rows 30,31 = 0)
#define OFF_BZ   68096u       // [32]
#define OFF_WR   68128u       // [240] (padded 0 beyond 230)
#define OFF_S0   68368u       // [16][32] padded initial state
#define OFF_MEAN 68880u       // [12][16][8]
#define OFF_STD  70416u       // [12][16][8]
#define OFF_BCUR 71952u       // [16000][200]
#define OFF_SCUR 3271952u     // [16000][32]
#define OFF_ACT  3783952u     // [12][16000][8]
#define OFF_RET  5319952u     // [16000]
#define OFF_TOPK 5335952u     // int [16][100]

// ---------------- threefry2x32 (JAX-exact) ----------------
__host__ __device__ __forceinline__ uint32_t tf_rotl(uint32_t x, int r) {
  return (x << r) | (x >> (32 - r));
}
__host__ __device__ __forceinline__ void tf2x32(uint32_t k0, uint32_t k1,
                                                uint32_t& x0, uint32_t& x1) {
  uint32_t k2 = k0 ^ k1 ^ 0x1BD11BDAu;
  x0 += k0; x1 += k1;
  x0 += x1; x1 = tf_rotl(x1, 13); x1 ^= x0;
  x0 += x1; x1 = tf_rotl(x1, 15); x1 ^= x0;
  x0 += x1; x1 = tf_rotl(x1, 26); x1 ^= x0;
  x0 += x1; x1 = tf_rotl(x1,  6); x1 ^= x0;
  x0 += k1; x1 += k2 + 1u;
  x0 += x1; x1 = tf_rotl(x1, 17); x1 ^= x0;
  x0 += x1; x1 = tf_rotl(x1, 29); x1 ^= x0;
  x0 += x1; x1 = tf_rotl(x1, 16); x1 ^= x0;
  x0 += x1; x1 = tf_rotl(x1, 24); x1 ^= x0;
  x0 += k2; x1 += k0 + 2u;
  x0 += x1; x1 = tf_rotl(x1, 13); x1 ^= x0;
  x0 += x1; x1 = tf_rotl(x1, 15); x1 ^= x0;
  x0 += x1; x1 = tf_rotl(x1, 26); x1 ^= x0;
  x0 += x1; x1 = tf_rotl(x1,  6); x1 ^= x0;
  x0 += k0; x1 += k1 + 3u;
  x0 += x1; x1 = tf_rotl(x1, 17); x1 ^= x0;
  x0 += x1; x1 = tf_rotl(x1, 29); x1 ^= x0;
  x0 += x1; x1 = tf_rotl(x1, 16); x1 ^= x0;
  x0 += x1; x1 = tf_rotl(x1, 24); x1 ^= x0;
  x0 += k1; x1 += k2 + 4u;
  x0 += x1; x1 = tf_rotl(x1, 13); x1 ^= x0;
  x0 += x1; x1 = tf_rotl(x1, 15); x1 ^= x0;
  x0 += x1; x1 = tf_rotl(x1, 26); x1 ^= x0;
  x0 += x1; x1 = tf_rotl(x1,  6); x1 ^= x0;
  x0 += k2; x1 += k0 + 5u;
}

__device__ __forceinline__ float bits_to_normal(uint32_t bits) {
  uint32_t fb = (bits >> 9) | 0x3F800000u;
  float f = __uint_as_float(fb) - 1.0f;          // [0,1)
  float u = f * 2.0f - 0.99999994f;              // scale==2.0f exactly
  u = fmaxf(-0.99999994f, u);
  float w = -log1pf(-u * u);
  float p;
  if (w < 5.0f) {
    w = w - 2.5f;
    p = 2.81022636e-08f;
    p = fmaf(p, w, 3.43273939e-07f);
    p = fmaf(p, w, -3.5233877e-06f);
    p = fmaf(p, w, -4.39150654e-06f);
    p = fmaf(p, w, 0.00021858087f);
    p = fmaf(p, w, -0.00125372503f);
    p = fmaf(p, w, -0.00417768164f);
    p = fmaf(p, w, 0.246640727f);
    p = fmaf(p, w, 1.50140941f);
  } else {
    w = sqrtf(w) - 3.0f;
    p = -0.000200214257f;
    p = fmaf(p, w, 0.000100950558f);
    p = fmaf(p, w, 0.00134934322f);
    p = fmaf(p, w, -0.00367342844f);
    p = fmaf(p, w, 0.00573950773f);
    p = fmaf(p, w, -0.0076224613f);
    p = fmaf(p, w, 0.00943887047f);
    p = fmaf(p, w, 1.00167406f);
    p = fmaf(p, w, 2.83297682f);
  }
  return 1.41421354f * (p * u);
}

// ---------------- prep: pack weights, init mean/std, pad s0 ----------------
__global__ __launch_bounds__(256) void k_prep(const float* Wb, const float* Ws_,
                                              const float* Wa, const float* bb,
                                              const float* Wz, const float* bz,
                                              const float* Wr, const float* state,
                                              float* ws) {
  int i = blockIdx.x * 256 + threadIdx.x;
  if (i < 61440) {
    int k = i >> 8, c = i & 255;
    float v = 0.f;
    if (c < HD) {
      if (k < 200)      v = Wb[k * HD + c];
      else if (k < 230) v = Ws_[(k - 200) * HD + c];
      else if (k < 236) v = Wa[(k - 230) * HD + c];
    }
    ws[OFF_WALL + i] = v;
  } else if (i < 61696) {
    int c = i - 61440;
    ws[i] = (c < HD) ? bb[c] : 0.f;
  } else if (i < 68096) {
    int j = i - 61696;
    int z = j / 200, k = j - z * 200;
    ws[i] = (z < ZD) ? Wz[k * ZD + z] : 0.f;      // WzT[z][k]
  } else if (i < 68128) {
    int z = i - 68096;
    ws[i] = (z < ZD) ? bz[z] : 0.f;
  } else if (i < 68368) {
    int k = i - 68128;
    ws[i] = (k < 230) ? Wr[k] : 0.f;
  } else if (i < 68880) {
    int j = i - 68368; int b = j >> 5, z = j & 31;
    ws[i] = (z < ZD) ? state[b * ZD + z] : 0.f;
  } else if (i < 70416) {
    ws[i] = 0.f;   // mean
  } else if (i < 71952) {
    ws[i] = 1.f;   // std
  }
}

// ---------------- actions = mean + std * normal(threefry) ----------------
__global__ __launch_bounds__(256) void k_actions(uint32_t k0, uint32_t k1, float* ws) {
  uint32_t idx = blockIdx.x * 256u + threadIdx.x;
  if (idx >= NELEM) return;
  uint32_t x0 = 0u, x1 = idx;
  tf2x32(k0, k1, x0, x1);
  float z = bits_to_normal(x0 ^ x1);
  uint32_t a = idx % 6u;  uint32_t q = idx / 6u;
  uint32_t c = q % 1000u; uint32_t q2 = q / 1000u;
  uint32_t b = q2 % 16u;  uint32_t t = q2 / 16u;
  uint32_t mi = (t * 16u + b) * 8u + a;
  float m = ws[OFF_MEAN + mi];
  float s = ws[OFF_STD + mi];
  ws[OFF_ACT + ((size_t)t * NROWS + b * 1000u + c) * 8u + a] = fmaf(s, z, m);
}

// ---------------- full 12-step rollout: NO LDS, NO barriers ----------------
// 32 rows/block, 8 rows/wave; each wave fully owns its rows end-to-end.
// b/s state round-trips through global (bcur/scur, L2-resident); W streamed
// from L2/L1 (VMEM pipe) instead of the saturated DS pipe. Stage-2 uses
// transposed WzT so its weight reads are b128.
__global__ __launch_bounds__(256) void k_roll(float* __restrict__ ws,
                                              const float* __restrict__ belief,
                                              const float* __restrict__ state,
                                              const float* __restrict__ br) {
  const int tid = threadIdx.x;
  const int wv = tid >> 6;
  const int ln = tid & 63;
  const int c0 = ln * 4;
  const bool colok = (c0 < HD);
  const int grow0 = blockIdx.x * 32 + wv * 8;   // wave's global row base

  const float* __restrict__ Wall = ws + OFF_WALL;
  const float* __restrict__ Wzt  = ws + OFF_WZT;
  const float* __restrict__ Wrp  = ws + OFF_WR;
  float* __restrict__ bcur = ws + OFF_BCUR;
  float* __restrict__ scur = ws + OFF_SCUR;

  // persistent per-lane constants
  float bbv[4];
  *(float4*)bbv = *(const float4*)(ws + OFF_BB + c0);
  float wr4[4] = {0.f, 0.f, 0.f, 0.f};
  if (colok) *(float4*)wr4 = *(const float4*)(Wrp + c0);
  const int z = ln & 31;
  const int rh = ln >> 5;              // half-wave: rows grow0+rh*4 .. +4
  const float bz_z = ws[OFF_BZ + z];
  const float wrz  = Wrp[200 + z];     // 0 for z>=30 (padded)
  const float br0 = br[0];

  // one-time init of this wave's 8 rows in bcur/scur (wave-private)
#pragma unroll
  for (int r = 0; r < 8; ++r) {
    const int row = grow0 + r;
    const int b = row / 1000;
    if (colok) {
      float4 v = *(const float4*)(belief + (size_t)b * HD + c0);
      *(float4*)(bcur + (size_t)row * HD + c0) = v;
    }
    if (ln < 32) {
      float v = (ln < ZD) ? state[(size_t)b * ZD + ln] : 0.f;
      scur[(size_t)row * 32 + ln] = v;
    }
  }
  float ret[8] = {0.f, 0.f, 0.f, 0.f, 0.f, 0.f, 0.f, 0.f};

  const float* __restrict__ bp = bcur + (size_t)grow0 * HD;   // wave's b rows
  const float* __restrict__ spp = scur + (size_t)grow0 * 32;  // wave's s rows

  for (int t = 0; t < TT; ++t) {
    const float* __restrict__ actp =
        ws + OFF_ACT + ((size_t)t * NROWS + grow0) * 8;

    float acc[8][4];
#pragma unroll
    for (int r = 0; r < 8; ++r) {
      acc[r][0] = bbv[0]; acc[r][1] = bbv[1]; acc[r][2] = bbv[2]; acc[r][3] = bbv[3];
    }

    // ---- region A: k in [0,200) from bcur (uniform b128 loads) ----
#pragma unroll 2
    for (int k = 0; k < 200; k += 4) {
      float xv[8][4];
#pragma unroll
      for (int r = 0; r < 8; ++r)
        *(float4*)xv[r] = *(const float4*)(bp + (size_t)r * HD + k);
#pragma unroll
      for (int i = 0; i < 4; ++i) {
        float wv4[4];
        *(float4*)wv4 = *(const float4*)(Wall + (size_t)(k + i) * 256 + c0);
#pragma unroll
        for (int r = 0; r < 8; ++r) {
          const float xs = xv[r][i];
          acc[r][0] = fmaf(xs, wv4[0], acc[r][0]);
          acc[r][1] = fmaf(xs, wv4[1], acc[r][1]);
          acc[r][2] = fmaf(xs, wv4[2], acc[r][2]);
          acc[r][3] = fmaf(xs, wv4[3], acc[r][3]);
        }
      }
    }
    // ---- region B: k in [200,230) from scur ----
#pragma unroll
    for (int kb = 0; kb < 28; kb += 4) {
      float xv[8][4];
#pragma unroll
      for (int r = 0; r < 8; ++r)
        *(float4*)xv[r] = *(const float4*)(spp + (size_t)r * 32 + kb);
#pragma unroll
      for (int i = 0; i < 4; ++i) {
        float wv4[4];
        *(float4*)wv4 = *(const float4*)(Wall + (size_t)(200 + kb + i) * 256 + c0);
#pragma unroll
        for (int r = 0; r < 8; ++r) {
          const float xs = xv[r][i];
          acc[r][0] = fmaf(xs, wv4[0], acc[r][0]);
          acc[r][1] = fmaf(xs, wv4[1], acc[r][1]);
          acc[r][2] = fmaf(xs, wv4[2], acc[r][2]);
          acc[r][3] = fmaf(xs, wv4[3], acc[r][3]);
        }
      }
    }
    {
      float xv[8][2];
#pragma unroll
      for (int r = 0; r < 8; ++r)
        *(float2*)xv[r] = *(const float2*)(spp + (size_t)r * 32 + 28);
#pragma unroll
      for (int i = 0; i < 2; ++i) {
        float wv4[4];
        *(float4*)wv4 = *(const float4*)(Wall + (size_t)(228 + i) * 256 + c0);
#pragma unroll
        for (int r = 0; r < 8; ++r) {
          const float xs = xv[r][i];
          acc[r][0] = fmaf(xs, wv4[0], acc[r][0]);
          acc[r][1] = fmaf(xs, wv4[1], acc[r][1]);
          acc[r][2] = fmaf(xs, wv4[2], acc[r][2]);
          acc[r][3] = fmaf(xs, wv4[3], acc[r][3]);
        }
      }
    }
    // ---- region C: k in [230,236) from actions (uniform) ----
    {
      float xa[8][4], xa2[8][2];
#pragma unroll
      for (int r = 0; r < 8; ++r) {
        *(float4*)xa[r]  = *(const float4*)(actp + (size_t)r * 8);
        *(float2*)xa2[r] = *(const float2*)(actp + (size_t)r * 8 + 4);
      }
#pragma unroll
      for (int i = 0; i < 4; ++i) {
        float wv4[4];
        *(float4*)wv4 = *(const float4*)(Wall + (size_t)(230 + i) * 256 + c0);
#pragma unroll
        for (int r = 0; r < 8; ++r) {
          const float xs = xa[r][i];
          acc[r][0] = fmaf(xs, wv4[0], acc[r][0]);
          acc[r][1] = fmaf(xs, wv4[1], acc[r][1]);
          acc[r][2] = fmaf(xs, wv4[2], acc[r][2]);
          acc[r][3] = fmaf(xs, wv4[3], acc[r][3]);
        }
      }
#pragma unroll
      for (int i = 0; i < 2; ++i) {
        float wv4[4];
        *(float4*)wv4 = *(const float4*)(Wall + (size_t)(234 + i) * 256 + c0);
#pragma unroll
        for (int r = 0; r < 8; ++r) {
          const float xs = xa2[r][i];
          acc[r][0] = fmaf(xs, wv4[0], acc[r][0]);
          acc[r][1] = fmaf(xs, wv4[1], acc[r][1]);
          acc[r][2] = fmaf(xs, wv4[2], acc[r][2]);
          acc[r][3] = fmaf(xs, wv4[3], acc[r][3]);
        }
      }
    }

    // ---- stage-1 epilogue: tanh, write b_new to bcur, h.Wr reward ----
#pragma unroll
    for (int r = 0; r < 8; ++r) {
      float h[4];
      h[0] = tanhf(acc[r][0]); h[1] = tanhf(acc[r][1]);
      h[2] = tanhf(acc[r][2]); h[3] = tanhf(acc[r][3]);
      if (colok) {
        *(float4*)(bcur + (size_t)(grow0 + r) * HD + c0) = *(float4*)h;
        ret[r] = fmaf(h[0], wr4[0], ret[r]);
        ret[r] = fmaf(h[1], wr4[1], ret[r]);
        ret[r] = fmaf(h[2], wr4[2], ret[r]);
        ret[r] = fmaf(h[3], wr4[3], ret[r]);
      }
    }
    // same-wave store->load ordering guaranteed via vmcnt (scratch-path rule)

    // ---- stage 2: half-wave rh owns 4 rows; lane z computes s_new[z] ----
    {
      const float* __restrict__ xrow = bcur + (size_t)(grow0 + rh * 4) * HD;
      const float* __restrict__ wzr = Wzt + (size_t)z * 200;
      float pz[4] = {0.f, 0.f, 0.f, 0.f};
#pragma unroll 2
      for (int k = 0; k < 200; k += 4) {
        float w4[4];
        *(float4*)w4 = *(const float4*)(wzr + k);
#pragma unroll
        for (int j = 0; j < 4; ++j) {
          float xA[4];
          *(float4*)xA = *(const float4*)(xrow + (size_t)j * HD + k);
          pz[j] = fmaf(xA[0], w4[0], pz[j]);
          pz[j] = fmaf(xA[1], w4[1], pz[j]);
          pz[j] = fmaf(xA[2], w4[2], pz[j]);
          pz[j] = fmaf(xA[3], w4[3], pz[j]);
        }
      }
      float sn[4];
#pragma unroll
      for (int j = 0; j < 4; ++j) {
        sn[j] = tanhf(pz[j] + bz_z);
        if (z < ZD) scur[(size_t)(grow0 + rh * 4 + j) * 32 + z] = sn[j];
      }
      // wrz==0 for z>=30 -> padded lanes contribute exact 0
      if (rh == 0) {
        ret[0] = fmaf(sn[0], wrz, ret[0]);
        ret[1] = fmaf(sn[1], wrz, ret[1]);
        ret[2] = fmaf(sn[2], wrz, ret[2]);
        ret[3] = fmaf(sn[3], wrz, ret[3]);
      } else {
        ret[4] = fmaf(sn[0], wrz, ret[4]);
        ret[5] = fmaf(sn[1], wrz, ret[5]);
        ret[6] = fmaf(sn[2], wrz, ret[6]);
        ret[7] = fmaf(sn[3], wrz, ret[7]);
      }
    }
  }

  // final: butterfly-reduce rewards across the wave, write 8 returns
#pragma unroll
  for (int r = 0; r < 8; ++r) {
#pragma unroll
    for (int m = 1; m < 64; m <<= 1) ret[r] += __shfl_xor(ret[r], m, 64);
  }
  if (ln < 8) {
    float v = (ln == 0) ? ret[0] : (ln == 1) ? ret[1] : (ln == 2) ? ret[2] :
              (ln == 3) ? ret[3] : (ln == 4) ? ret[4] : (ln == 5) ? ret[5] :
              (ln == 6) ? ret[6] : ret[7];
    ws[OFF_RET + grow0 + ln] = v + 12.0f * br0;
  }
}

// ---------------- top-k via full bitonic sort (desc, ties by index) ----------------
__global__ __launch_bounds__(1024) void k_topk(float* ws) {
  __shared__ float sv[1024];
  __shared__ int si[1024];
  const int b = blockIdx.x, tid = threadIdx.x;
  const float* ret = ws + OFF_RET + b * 1000;
  sv[tid] = (tid < 1000) ? ret[tid] : -3.0e38f;
  si[tid] = tid;
  __syncthreads();
  for (int k = 2; k <= 1024; k <<= 1) {
    for (int j = k >> 1; j > 0; j >>= 1) {
      int ixj = tid ^ j;
      if (ixj > tid) {
        float v1 = sv[tid], v2 = sv[ixj];
        int i1 = si[tid], i2 = si[ixj];
        bool gt = (v1 < v2) || (v1 == v2 && i1 > i2);
        bool up = ((tid & k) == 0);
        if (up ? gt : !gt) {
          sv[tid] = v2; sv[ixj] = v1;
          si[tid] = i2; si[ixj] = i1;
        }
      }
      __syncthreads();
    }
  }
  int* topk = (int*)(ws + OFF_TOPK);
  if (tid < 100) topk[b * 100 + tid] = si[tid];
}

// ---------------- mean/std over elites: one wave per (t,b,a) ----------------
__global__ __launch_bounds__(256) void k_meanstd(float* ws) {
  const int g = blockIdx.x * 4 + (threadIdx.x >> 6);  // 0..1151
  const int ln = threadIdx.x & 63;
  const int t = g / 96; const int rem = g - t * 96;
  const int b = rem / 6; const int a = rem - b * 6;
  const int* topk = (const int*)(ws + OFF_TOPK) + b * 100;
  const float* act = ws + OFF_ACT + (size_t)t * NROWS * 8;
  const bool h2 = (ln < 36);
  int c1 = topk[ln];
  float x1 = act[((size_t)b * 1000 + c1) * 8 + a];
  float x2 = 0.f;
  if (h2) { int cc = topk[ln + 64]; x2 = act[((size_t)b * 1000 + cc) * 8 + a]; }
  float s = x1 + x2;
#pragma unroll
  for (int m = 1; m < 64; m <<= 1) s += __shfl_xor(s, m, 64);
  const float mean = s / 100.0f;
  float d = x1 - mean; float qq = d * d;
  if (h2) { float d2 = x2 - mean; qq += d2 * d2; }
#pragma unroll
  for (int m = 1; m < 64; m <<= 1) qq += __shfl_xor(qq, m, 64);
  if (ln == 0) {
    ws[OFF_MEAN + ((size_t)t * 16 + b) * 8 + a] = mean;
    ws[OFF_STD  + ((size_t)t * 16 + b) * 8 + a] = sqrtf(qq / 100.0f);
  }
}

__global__ void k_out(const float* ws, float* out) {
  int i = threadIdx.x;
  if (i < 96) out[i] = ws[OFF_MEAN + (i / 6) * 8 + (i % 6)];
}

extern "C" void kernel_launch(void* const* d_in, const int* in_sizes, int n_in,
                              void* d_out, int out_size, void* d_ws, size_t ws_size,
                              hipStream_t stream) {
  const float* belief = (const float*)d_in[0];
  const float* state  = (const float*)d_in[1];
  const float* Wb  = (const float*)d_in[2];
  const float* Ws_ = (const float*)d_in[3];
  const float* Wa  = (const float*)d_in[4];
  const float* bb  = (const float*)d_in[5];
  const float* Wz  = (const float*)d_in[6];
  const float* bz  = (const float*)d_in[7];
  const float* Wr  = (const float*)d_in[8];
  const float* br  = (const float*)d_in[9];
  float* ws = (float*)d_ws;   // needs ~21.4 MB

  k_prep<<<282, 256, 0, stream>>>(Wb, Ws_, Wa, bb, Wz, bz, Wr, state, ws);

  for (int it = 0; it < NITERS; ++it) {
    uint32_t f0 = 0u, f1 = (uint32_t)it;
    tf2x32(0u, 42u, f0, f1);
    k_actions<<<4500, 256, 0, stream>>>(f0, f1, ws);
    k_roll<<<500, 256, 0, stream>>>(ws, belief, state, br);
    k_topk<<<16, 1024, 0, stream>>>(ws);
    k_meanstd<<<288, 256, 0, stream>>>(ws);
  }
  k_out<<<1, 128, 0, stream>>>(ws, (float*)d_out);
}

// Round 7
// 2598.886 us; speedup vs baseline: 8.3318x; 8.3318x over previous
//
#include <hip/hip_runtime.h>
#include <stdint.h>

#define TT 12
#define NITERS 10
#define NCAND 1000
#define AD 6
#define BD 16
#define HD 200
#define ZD 30
#define NROWS 16000
#define NELEM 1152000u

// ws layout (u32/float offsets)
#define OFF_WSW  0u          // u32[53248]  W_all pre-split+swizzled B-frags [hl][13][8][64][4]
#define OFF_WZSW 53248u      // u32[7168]   Wz  [hl][2][7][64][4]
#define OFF_WRSW 60416u      // u32[4096]   Wr' [hl][8][64][4] (col0 only)
#define OFF_MEAN 64512u      // f32[12][16][8]
#define OFF_STD  66048u      // f32[12][16][8]
#define OFF_ACT  67584u      // f32[12][16000][8]
#define OFF_RET  1603584u    // f32[16000]
#define OFF_TOPK 1619584u    // int[16][100]

typedef __attribute__((ext_vector_type(8))) short short8v;
typedef __attribute__((ext_vector_type(4))) float f32x4;

// ---------------- threefry2x32 (JAX-exact) ----------------
__host__ __device__ __forceinline__ uint32_t tf_rotl(uint32_t x, int r) {
  return (x << r) | (x >> (32 - r));
}
__host__ __device__ __forceinline__ void tf2x32(uint32_t k0, uint32_t k1,
                                                uint32_t& x0, uint32_t& x1) {
  uint32_t k2 = k0 ^ k1 ^ 0x1BD11BDAu;
  x0 += k0; x1 += k1;
  x0 += x1; x1 = tf_rotl(x1, 13); x1 ^= x0;
  x0 += x1; x1 = tf_rotl(x1, 15); x1 ^= x0;
  x0 += x1; x1 = tf_rotl(x1, 26); x1 ^= x0;
  x0 += x1; x1 = tf_rotl(x1,  6); x1 ^= x0;
  x0 += k1; x1 += k2 + 1u;
  x0 += x1; x1 = tf_rotl(x1, 17); x1 ^= x0;
  x0 += x1; x1 = tf_rotl(x1, 29); x1 ^= x0;
  x0 += x1; x1 = tf_rotl(x1, 16); x1 ^= x0;
  x0 += x1; x1 = tf_rotl(x1, 24); x1 ^= x0;
  x0 += k2; x1 += k0 + 2u;
  x0 += x1; x1 = tf_rotl(x1, 13); x1 ^= x0;
  x0 += x1; x1 = tf_rotl(x1, 15); x1 ^= x0;
  x0 += x1; x1 = tf_rotl(x1, 26); x1 ^= x0;
  x0 += x1; x1 = tf_rotl(x1,  6); x1 ^= x0;
  x0 += k0; x1 += k1 + 3u;
  x0 += x1; x1 = tf_rotl(x1, 17); x1 ^= x0;
  x0 += x1; x1 = tf_rotl(x1, 29); x1 ^= x0;
  x0 += x1; x1 = tf_rotl(x1, 16); x1 ^= x0;
  x0 += x1; x1 = tf_rotl(x1, 24); x1 ^= x0;
  x0 += k1; x1 += k2 + 4u;
  x0 += x1; x1 = tf_rotl(x1, 13); x1 ^= x0;
  x0 += x1; x1 = tf_rotl(x1, 15); x1 ^= x0;
  x0 += x1; x1 = tf_rotl(x1, 26); x1 ^= x0;
  x0 += x1; x1 = tf_rotl(x1,  6); x1 ^= x0;
  x0 += k2; x1 += k0 + 5u;
}

__device__ __forceinline__ float bits_to_normal(uint32_t bits) {
  uint32_t fb = (bits >> 9) | 0x3F800000u;
  float f = __uint_as_float(fb) - 1.0f;          // [0,1)
  float u = f * 2.0f - 0.99999994f;
  u = fmaxf(-0.99999994f, u);
  float w = -log1pf(-u * u);
  float p;
  if (w < 5.0f) {
    w = w - 2.5f;
    p = 2.81022636e-08f;
    p = fmaf(p, w, 3.43273939e-07f);
    p = fmaf(p, w, -3.5233877e-06f);
    p = fmaf(p, w, -4.39150654e-06f);
    p = fmaf(p, w, 0.00021858087f);
    p = fmaf(p, w, -0.00125372503f);
    p = fmaf(p, w, -0.00417768164f);
    p = fmaf(p, w, 0.246640727f);
    p = fmaf(p, w, 1.50140941f);
  } else {
    w = sqrtf(w) - 3.0f;
    p = -0.000200214257f;
    p = fmaf(p, w, 0.000100950558f);
    p = fmaf(p, w, 0.00134934322f);
    p = fmaf(p, w, -0.00367342844f);
    p = fmaf(p, w, 0.00573950773f);
    p = fmaf(p, w, -0.0076224613f);
    p = fmaf(p, w, 0.00943887047f);
    p = fmaf(p, w, 1.00167406f);
    p = fmaf(p, w, 2.83297682f);
  }
  return 1.41421354f * (p * u);
}

// bf16 round-to-nearest-even (returns 16-bit pattern)
__device__ __forceinline__ uint32_t bf16rne(float x) {
  uint32_t u = __float_as_uint(x);
  return (u + 0x7FFFu + ((u >> 16) & 1u)) >> 16;
}

// ---------------- prep: split+swizzle weights into B-frag order ----------------
__global__ __launch_bounds__(256) void k_prep(const float* Wb, const float* Ws_,
                                              const float* Wa, const float* Wz,
                                              const float* Wr, float* ws) {
  int i = blockIdx.x * 256 + threadIdx.x;
  uint32_t* wsu = (uint32_t*)ws;
  if (i < 53248) {
    int d = i & 3; int t = i >> 2;
    int lane = t & 63; t >>= 6;
    int ks = t & 7; t >>= 3;
    int nt = t % 13; int hl = t / 13;
    int col = nt * 16 + (lane & 15);
    int kb = ks * 32 + (lane >> 4) * 8 + d * 2;
    uint32_t out = 0;
    for (int e = 0; e < 2; ++e) {
      int k = kb + e;
      float v = 0.f;
      if (col < 200) {
        if (k < 200)      v = Wb[k * 200 + col];
        else if (k < 230) v = Ws_[(k - 200) * 200 + col];
        else if (k < 236) v = Wa[(k - 230) * 200 + col];
      }
      uint32_t hi = bf16rne(v);
      float hf = __uint_as_float(hi << 16);
      uint32_t lo = bf16rne(v - hf);
      uint32_t bits = (hl == 0) ? hi : lo;
      out |= (bits & 0xFFFFu) << (16 * e);
    }
    wsu[OFF_WSW + i] = out;
  } else if (i < 60416) {
    int j = i - 53248;
    int d = j & 3; int t = j >> 2;
    int lane = t & 63; t >>= 6;
    int ks = t % 7; t /= 7;
    int nt = t & 1; int hl = t >> 1;
    int col = nt * 16 + (lane & 15);
    int kb = ks * 32 + (lane >> 4) * 8 + d * 2;
    uint32_t out = 0;
    for (int e = 0; e < 2; ++e) {
      int k = kb + e;
      float v = (k < 200 && col < 30) ? Wz[k * 30 + col] : 0.f;
      uint32_t hi = bf16rne(v);
      float hf = __uint_as_float(hi << 16);
      uint32_t lo = bf16rne(v - hf);
      uint32_t bits = (hl == 0) ? hi : lo;
      out |= (bits & 0xFFFFu) << (16 * e);
    }
    wsu[OFF_WZSW + j] = out;
  } else if (i < 64512) {
    int j = i - 60416;
    int d = j & 3; int t = j >> 2;
    int lane = t & 63; t >>= 6;
    int ks = t & 7; int hl = t >> 3;
    int col = lane & 15;
    int kb = ks * 32 + (lane >> 4) * 8 + d * 2;
    uint32_t out = 0;
    for (int e = 0; e < 2; ++e) {
      int k = kb + e;
      float v = (col == 0 && k < 230) ? Wr[k] : 0.f;
      uint32_t hi = bf16rne(v);
      float hf = __uint_as_float(hi << 16);
      uint32_t lo = bf16rne(v - hf);
      uint32_t bits = (hl == 0) ? hi : lo;
      out |= (bits & 0xFFFFu) << (16 * e);
    }
    wsu[OFF_WRSW + j] = out;
  } else if (i < 66048) {
    ws[i] = 0.f;   // mean
  } else if (i < 67584) {
    ws[i] = 1.f;   // std
  }
}

// ---------------- actions = mean + std * normal(threefry) ----------------
__global__ __launch_bounds__(256) void k_actions(uint32_t k0, uint32_t k1, float* ws) {
  uint32_t idx = blockIdx.x * 256u + threadIdx.x;
  if (idx >= NELEM) return;
  uint32_t x0 = 0u, x1 = idx;
  tf2x32(k0, k1, x0, x1);
  float z = bits_to_normal(x0 ^ x1);
  uint32_t a = idx % 6u;  uint32_t q = idx / 6u;
  uint32_t c = q % 1000u; uint32_t q2 = q / 1000u;
  uint32_t b = q2 % 16u;  uint32_t t = q2 / 16u;
  uint32_t mi = (t * 16u + b) * 8u + a;
  float m = ws[OFF_MEAN + mi];
  float s = ws[OFF_STD + mi];
  ws[OFF_ACT + ((size_t)t * NROWS + b * 1000u + c) * 8u + a] = fmaf(s, z, m);
}

// ---------------- full 12-step rollout via split-bf16 MFMA (4-pass) ----------------
// 64 rows/block, 4 waves. x resident in LDS as bf16 hi/lo pairs; waves split N
// for stage-1 (tiles 4/3/3/3 of 13), split M for stage-2 + reward. Reward
// accumulates in a persistent MFMA C-operand across all 12 steps.
__global__ __launch_bounds__(256) void k_roll(float* __restrict__ ws,
                                              const float* __restrict__ belief,
                                              const float* __restrict__ state,
                                              const float* __restrict__ bbp,
                                              const float* __restrict__ bzp,
                                              const float* __restrict__ brp) {
  __shared__ unsigned short xh[64 * 280];   // bf16 hi, row stride 280 (bank-friendly)
  __shared__ unsigned short xl[64 * 280];   // bf16 lo

  const int tid = threadIdx.x;
  const int wv = tid >> 6;
  const int ln = tid & 63;
  const int r = ln & 15;
  const int kh = ln >> 4;
  const int grow0 = blockIdx.x * 64;
  const uint32_t* __restrict__ wsu = (const uint32_t*)ws;

  const int NT  = (wv == 0) ? 4 : 3;          // stage-1 N-tiles per wave
  const int ntb = (wv == 0) ? 0 : (1 + wv * 3);

  float bbv[4];
#pragma unroll
  for (int j = 0; j < 4; ++j) {
    int col = (ntb + j) * 16 + r;
    bbv[j] = (j < NT && col < 200) ? bbp[col] : 0.f;
  }
  float bzv[2];
#pragma unroll
  for (int j = 0; j < 2; ++j) {
    int col = j * 16 + r;
    bzv[j] = (col < 30) ? bzp[col] : 0.f;
  }
  const float br0 = brp[0];

  // init x: k<200 belief, 200..230 state, rest 0 (incl. action+pad region)
  for (int idx = tid; idx < 64 * 256; idx += 256) {
    int row = idx >> 8, k = idx & 255;
    int b = (grow0 + row) / 1000;
    float v = 0.f;
    if (k < 200) v = belief[b * 200 + k];
    else if (k < 230) v = state[b * 30 + (k - 200)];
    uint32_t hi = bf16rne(v);
    float hf = __uint_as_float(hi << 16);
    uint32_t lo = bf16rne(v - hf);
    xh[row * 280 + k] = (unsigned short)hi;
    xl[row * 280 + k] = (unsigned short)lo;
  }

  f32x4 racc = {0.f, 0.f, 0.f, 0.f};

#pragma unroll 1
  for (int t = 0; t < TT; ++t) {
    // write this step's actions (k 230..236) for all 64 rows
    const float* actp = ws + OFF_ACT + ((size_t)t * NROWS + grow0) * 8;
    for (int idx = tid; idx < 384; idx += 256) {
      int row = idx / 6, a = idx - row * 6;
      float v = actp[row * 8 + a];
      uint32_t hi = bf16rne(v);
      float hf = __uint_as_float(hi << 16);
      uint32_t lo = bf16rne(v - hf);
      xh[row * 280 + 230 + a] = (unsigned short)hi;
      xl[row * 280 + 230 + a] = (unsigned short)lo;
    }
    __syncthreads();                           // B0: actions ready

    // ---- stage 1: h = tanh(x @ W_all + bb); wave covers 64 rows x its N-tiles ----
    f32x4 acc[4][4];
#pragma unroll
    for (int m = 0; m < 4; ++m)
#pragma unroll
      for (int j = 0; j < 4; ++j) {
        f32x4 c = {bbv[j], bbv[j], bbv[j], bbv[j]};
        acc[m][j] = c;
      }

#pragma unroll 2
    for (int ks = 0; ks < 8; ++ks) {
      short8v Ah[4], Al[4];
      const int kbase = ks * 32 + kh * 8;
#pragma unroll
      for (int m = 0; m < 4; ++m) {
        int off = (m * 16 + r) * 280 + kbase;
        Ah[m] = *(const short8v*)&xh[off];
        Al[m] = *(const short8v*)&xl[off];
      }
#pragma unroll
      for (int j = 0; j < 4; ++j) {
        if (j < NT) {
          const int nt = ntb + j;
          const short8v Bh = *(const short8v*)(wsu + OFF_WSW + (((0 * 13 + nt) * 8 + ks) * 64 + ln) * 4);
          const short8v Bl = *(const short8v*)(wsu + OFF_WSW + (((1 * 13 + nt) * 8 + ks) * 64 + ln) * 4);
#pragma unroll
          for (int m = 0; m < 4; ++m) {
            f32x4 c = acc[m][j];
            c = __builtin_amdgcn_mfma_f32_16x16x32_bf16(Al[m], Bl, c, 0, 0, 0);
            c = __builtin_amdgcn_mfma_f32_16x16x32_bf16(Ah[m], Bl, c, 0, 0, 0);
            c = __builtin_amdgcn_mfma_f32_16x16x32_bf16(Al[m], Bh, c, 0, 0, 0);
            c = __builtin_amdgcn_mfma_f32_16x16x32_bf16(Ah[m], Bh, c, 0, 0, 0);
            acc[m][j] = c;
          }
        }
      }
    }
    __syncthreads();                           // B1: all A-reads done before h-writes

    // h epilogue: tanh, split, write back (D: row=(ln>>4)*4+reg, col=ln&15)
#pragma unroll
    for (int j = 0; j < 4; ++j) {
      int col = (ntb + j) * 16 + r;
      if (j < NT && col < 200) {
#pragma unroll
        for (int m = 0; m < 4; ++m) {
#pragma unroll
          for (int reg = 0; reg < 4; ++reg) {
            int row = m * 16 + kh * 4 + reg;
            float h = tanhf(acc[m][j][reg]);
            uint32_t hi = bf16rne(h);
            float hf = __uint_as_float(hi << 16);
            uint32_t lo = bf16rne(h - hf);
            xh[row * 280 + col] = (unsigned short)hi;
            xl[row * 280 + col] = (unsigned short)lo;
          }
        }
      }
    }
    __syncthreads();                           // B2: h complete

    // ---- stage 2: s = tanh(h @ Wz + bz); wave owns M-tile wv (16 rows) ----
    f32x4 acc2[2];
    {
      f32x4 c0 = {bzv[0], bzv[0], bzv[0], bzv[0]};
      f32x4 c1 = {bzv[1], bzv[1], bzv[1], bzv[1]};
      acc2[0] = c0; acc2[1] = c1;
    }
#pragma unroll
    for (int ks = 0; ks < 7; ++ks) {          // K=224; k 200..223 x Wz==0 benign
      int off = (wv * 16 + r) * 280 + ks * 32 + kh * 8;
      short8v Ah2 = *(const short8v*)&xh[off];
      short8v Al2 = *(const short8v*)&xl[off];
#pragma unroll
      for (int j = 0; j < 2; ++j) {
        const short8v Bh = *(const short8v*)(wsu + OFF_WZSW + (((0 * 2 + j) * 7 + ks) * 64 + ln) * 4);
        const short8v Bl = *(const short8v*)(wsu + OFF_WZSW + (((1 * 2 + j) * 7 + ks) * 64 + ln) * 4);
        f32x4 c = acc2[j];
        c = __builtin_amdgcn_mfma_f32_16x16x32_bf16(Al2, Bl, c, 0, 0, 0);
        c = __builtin_amdgcn_mfma_f32_16x16x32_bf16(Ah2, Bl, c, 0, 0, 0);
        c = __builtin_amdgcn_mfma_f32_16x16x32_bf16(Al2, Bh, c, 0, 0, 0);
        c = __builtin_amdgcn_mfma_f32_16x16x32_bf16(Ah2, Bh, c, 0, 0, 0);
        acc2[j] = c;
      }
    }
    // s epilogue: write k 200..230 of own M-tile rows
#pragma unroll
    for (int j = 0; j < 2; ++j) {
      int col = j * 16 + r;
      if (col < 30) {
#pragma unroll
        for (int reg = 0; reg < 4; ++reg) {
          int row = wv * 16 + kh * 4 + reg;
          float s = tanhf(acc2[j][reg]);
          uint32_t hi = bf16rne(s);
          float hf = __uint_as_float(hi << 16);
          uint32_t lo = bf16rne(s - hf);
          xh[row * 280 + 200 + col] = (unsigned short)hi;
          xl[row * 280 + 200 + col] = (unsigned short)lo;
        }
      }
    }
    __syncthreads();                           // B3: s complete

    // ---- reward: racc += [h|s] @ Wr' (col 0); persistent across t ----
#pragma unroll
    for (int ks = 0; ks < 8; ++ks) {
      int off = (wv * 16 + r) * 280 + ks * 32 + kh * 8;
      short8v Ah3 = *(const short8v*)&xh[off];
      short8v Al3 = *(const short8v*)&xl[off];
      const short8v Bh = *(const short8v*)(wsu + OFF_WRSW + ((0 * 8 + ks) * 64 + ln) * 4);
      const short8v Bl = *(const short8v*)(wsu + OFF_WRSW + ((1 * 8 + ks) * 64 + ln) * 4);
      racc = __builtin_amdgcn_mfma_f32_16x16x32_bf16(Al3, Bl, racc, 0, 0, 0);
      racc = __builtin_amdgcn_mfma_f32_16x16x32_bf16(Ah3, Bl, racc, 0, 0, 0);
      racc = __builtin_amdgcn_mfma_f32_16x16x32_bf16(Al3, Bh, racc, 0, 0, 0);
      racc = __builtin_amdgcn_mfma_f32_16x16x32_bf16(Ah3, Bh, racc, 0, 0, 0);
    }
    // next iteration's action writes only race reward reads where Wr'==0: benign
  }

  if ((ln & 15) == 0) {
#pragma unroll
    for (int reg = 0; reg < 4; ++reg) {
      int row = wv * 16 + kh * 4 + reg;
      ws[OFF_RET + grow0 + row] = racc[reg] + 12.0f * br0;
    }
  }
}

// ---------------- top-k via full bitonic sort (desc, ties by index) ----------------
__global__ __launch_bounds__(1024) void k_topk(float* ws) {
  __shared__ float sv[1024];
  __shared__ int si[1024];
  const int b = blockIdx.x, tid = threadIdx.x;
  const float* ret = ws + OFF_RET + b * 1000;
  sv[tid] = (tid < 1000) ? ret[tid] : -3.0e38f;
  si[tid] = tid;
  __syncthreads();
  for (int k = 2; k <= 1024; k <<= 1) {
    for (int j = k >> 1; j > 0; j >>= 1) {
      int ixj = tid ^ j;
      if (ixj > tid) {
        float v1 = sv[tid], v2 = sv[ixj];
        int i1 = si[tid], i2 = si[ixj];
        bool gt = (v1 < v2) || (v1 == v2 && i1 > i2);
        bool up = ((tid & k) == 0);
        if (up ? gt : !gt) {
          sv[tid] = v2; sv[ixj] = v1;
          si[tid] = i2; si[ixj] = i1;
        }
      }
      __syncthreads();
    }
  }
  int* topk = (int*)(ws + OFF_TOPK);
  if (tid < 100) topk[b * 100 + tid] = si[tid];
}

// ---------------- mean/std over elites: one wave per (t,b,a) ----------------
__global__ __launch_bounds__(256) void k_meanstd(float* ws) {
  const int g = blockIdx.x * 4 + (threadIdx.x >> 6);  // 0..1151
  const int ln = threadIdx.x & 63;
  const int t = g / 96; const int rem = g - t * 96;
  const int b = rem / 6; const int a = rem - b * 6;
  const int* topk = (const int*)(ws + OFF_TOPK) + b * 100;
  const float* act = ws + OFF_ACT + (size_t)t * NROWS * 8;
  const bool h2 = (ln < 36);
  int c1 = topk[ln];
  float x1 = act[((size_t)b * 1000 + c1) * 8 + a];
  float x2 = 0.f;
  if (h2) { int cc = topk[ln + 64]; x2 = act[((size_t)b * 1000 + cc) * 8 + a]; }
  float s = x1 + x2;
#pragma unroll
  for (int m = 1; m < 64; m <<= 1) s += __shfl_xor(s, m, 64);
  const float mean = s / 100.0f;
  float d = x1 - mean; float qq = d * d;
  if (h2) { float d2 = x2 - mean; qq += d2 * d2; }
#pragma unroll
  for (int m = 1; m < 64; m <<= 1) qq += __shfl_xor(qq, m, 64);
  if (ln == 0) {
    ws[OFF_MEAN + ((size_t)t * 16 + b) * 8 + a] = mean;
    ws[OFF_STD  + ((size_t)t * 16 + b) * 8 + a] = sqrtf(qq / 100.0f);
  }
}

__global__ void k_out(const float* ws, float* out) {
  int i = threadIdx.x;
  if (i < 96) out[i] = ws[OFF_MEAN + (i / 6) * 8 + (i % 6)];
}

extern "C" void kernel_launch(void* const* d_in, const int* in_sizes, int n_in,
                              void* d_out, int out_size, void* d_ws, size_t ws_size,
                              hipStream_t stream) {
  const float* belief = (const float*)d_in[0];
  const float* state  = (const float*)d_in[1];
  const float* Wb  = (const float*)d_in[2];
  const float* Ws_ = (const float*)d_in[3];
  const float* Wa  = (const float*)d_in[4];
  const float* bb  = (const float*)d_in[5];
  const float* Wz  = (const float*)d_in[6];
  const float* bz  = (const float*)d_in[7];
  const float* Wr  = (const float*)d_in[8];
  const float* br  = (const float*)d_in[9];
  float* ws = (float*)d_ws;   // needs ~6.5 MB

  k_prep<<<264, 256, 0, stream>>>(Wb, Ws_, Wa, Wz, Wr, ws);

  for (int it = 0; it < NITERS; ++it) {
    uint32_t f0 = 0u, f1 = (uint32_t)it;
    tf2x32(0u, 42u, f0, f1);
    k_actions<<<4500, 256, 0, stream>>>(f0, f1, ws);
    k_roll<<<250, 256, 0, stream>>>(ws, belief, state, bb, bz, br);
    k_topk<<<16, 1024, 0, stream>>>(ws);
    k_meanstd<<<288, 256, 0, stream>>>(ws);
  }
  k_out<<<1, 128, 0, stream>>>(ws, (float*)d_out);
}

// Round 10
// 1852.244 us; speedup vs baseline: 11.6904x; 1.4031x over previous
//
#include <hip/hip_runtime.h>
#include <stdint.h>

#define TT 12
#define NITERS 10
#define NCAND 1000
#define AD 6
#define BD 16
#define HD 200
#define ZD 30
#define NROWS 16000
#define NELEM 1152000u

// ws layout (u32/float offsets)
#define OFF_WSW  0u          // u32[53248]  W_all pre-split+swizzled B-frags [hl][13][8][64][4]
#define OFF_WZSW 53248u      // u32[7168]   Wz  [hl][2][7][64][4]
#define OFF_WRSW 60416u      // u32[4096]   Wr' [hl][8][64][4] (col0 only)
#define OFF_MEAN 64512u      // f32[12][16][8]
#define OFF_STD  66048u      // f32[12][16][8]
#define OFF_ACT  67584u      // f32[12][16000][8]
#define OFF_RET  1603584u    // f32[16000]
#define OFF_TOPK 1619584u    // int[16][100]

typedef __attribute__((ext_vector_type(8))) short short8v;
typedef __attribute__((ext_vector_type(4))) float f32x4;

// ---------------- threefry2x32 (JAX-exact) ----------------
__host__ __device__ __forceinline__ uint32_t tf_rotl(uint32_t x, int r) {
  return (x << r) | (x >> (32 - r));
}
__host__ __device__ __forceinline__ void tf2x32(uint32_t k0, uint32_t k1,
                                                uint32_t& x0, uint32_t& x1) {
  uint32_t k2 = k0 ^ k1 ^ 0x1BD11BDAu;
  x0 += k0; x1 += k1;
  x0 += x1; x1 = tf_rotl(x1, 13); x1 ^= x0;
  x0 += x1; x1 = tf_rotl(x1, 15); x1 ^= x0;
  x0 += x1; x1 = tf_rotl(x1, 26); x1 ^= x0;
  x0 += x1; x1 = tf_rotl(x1,  6); x1 ^= x0;
  x0 += k1; x1 += k2 + 1u;
  x0 += x1; x1 = tf_rotl(x1, 17); x1 ^= x0;
  x0 += x1; x1 = tf_rotl(x1, 29); x1 ^= x0;
  x0 += x1; x1 = tf_rotl(x1, 16); x1 ^= x0;
  x0 += x1; x1 = tf_rotl(x1, 24); x1 ^= x0;
  x0 += k2; x1 += k0 + 2u;
  x0 += x1; x1 = tf_rotl(x1, 13); x1 ^= x0;
  x0 += x1; x1 = tf_rotl(x1, 15); x1 ^= x0;
  x0 += x1; x1 = tf_rotl(x1, 26); x1 ^= x0;
  x0 += x1; x1 = tf_rotl(x1,  6); x1 ^= x0;
  x0 += k0; x1 += k1 + 3u;
  x0 += x1; x1 = tf_rotl(x1, 17); x1 ^= x0;
  x0 += x1; x1 = tf_rotl(x1, 29); x1 ^= x0;
  x0 += x1; x1 = tf_rotl(x1, 16); x1 ^= x0;
  x0 += x1; x1 = tf_rotl(x1, 24); x1 ^= x0;
  x0 += k1; x1 += k2 + 4u;
  x0 += x1; x1 = tf_rotl(x1, 13); x1 ^= x0;
  x0 += x1; x1 = tf_rotl(x1, 15); x1 ^= x0;
  x0 += x1; x1 = tf_rotl(x1, 26); x1 ^= x0;
  x0 += x1; x1 = tf_rotl(x1,  6); x1 ^= x0;
  x0 += k2; x1 += k0 + 5u;
}

__device__ __forceinline__ float bits_to_normal(uint32_t bits) {
  uint32_t fb = (bits >> 9) | 0x3F800000u;
  float f = __uint_as_float(fb) - 1.0f;          // [0,1)
  float u = f * 2.0f - 0.99999994f;
  u = fmaxf(-0.99999994f, u);
  float w = -log1pf(-u * u);
  float p;
  if (w < 5.0f) {
    w = w - 2.5f;
    p = 2.81022636e-08f;
    p = fmaf(p, w, 3.43273939e-07f);
    p = fmaf(p, w, -3.5233877e-06f);
    p = fmaf(p, w, -4.39150654e-06f);
    p = fmaf(p, w, 0.00021858087f);
    p = fmaf(p, w, -0.00125372503f);
    p = fmaf(p, w, -0.00417768164f);
    p = fmaf(p, w, 0.246640727f);
    p = fmaf(p, w, 1.50140941f);
  } else {
    w = sqrtf(w) - 3.0f;
    p = -0.000200214257f;
    p = fmaf(p, w, 0.000100950558f);
    p = fmaf(p, w, 0.00134934322f);
    p = fmaf(p, w, -0.00367342844f);
    p = fmaf(p, w, 0.00573950773f);
    p = fmaf(p, w, -0.0076224613f);
    p = fmaf(p, w, 0.00943887047f);
    p = fmaf(p, w, 1.00167406f);
    p = fmaf(p, w, 2.83297682f);
  }
  return 1.41421354f * (p * u);
}

// bf16 round-to-nearest-even (returns 16-bit pattern)
__device__ __forceinline__ uint32_t bf16rne(float x) {
  uint32_t u = __float_as_uint(x);
  return (u + 0x7FFFu + ((u >> 16) & 1u)) >> 16;
}

// ---------------- prep: split+swizzle weights into B-frag order ----------------
__global__ __launch_bounds__(256) void k_prep(const float* Wb, const float* Ws_,
                                              const float* Wa, const float* Wz,
                                              const float* Wr, float* ws) {
  int i = blockIdx.x * 256 + threadIdx.x;
  uint32_t* wsu = (uint32_t*)ws;
  if (i < 53248) {
    int d = i & 3; int t = i >> 2;
    int lane = t & 63; t >>= 6;
    int ks = t & 7; t >>= 3;
    int nt = t % 13; int hl = t / 13;
    int col = nt * 16 + (lane & 15);
    int kb = ks * 32 + (lane >> 4) * 8 + d * 2;
    uint32_t out = 0;
    for (int e = 0; e < 2; ++e) {
      int k = kb + e;
      float v = 0.f;
      if (col < 200) {
        if (k < 200)      v = Wb[k * 200 + col];
        else if (k < 230) v = Ws_[(k - 200) * 200 + col];
        else if (k < 236) v = Wa[(k - 230) * 200 + col];
      }
      uint32_t hi = bf16rne(v);
      float hf = __uint_as_float(hi << 16);
      uint32_t lo = bf16rne(v - hf);
      uint32_t bits = (hl == 0) ? hi : lo;
      out |= (bits & 0xFFFFu) << (16 * e);
    }
    wsu[OFF_WSW + i] = out;
  } else if (i < 60416) {
    int j = i - 53248;
    int d = j & 3; int t = j >> 2;
    int lane = t & 63; t >>= 6;
    int ks = t % 7; t /= 7;
    int nt = t & 1; int hl = t >> 1;
    int col = nt * 16 + (lane & 15);
    int kb = ks * 32 + (lane >> 4) * 8 + d * 2;
    uint32_t out = 0;
    for (int e = 0; e < 2; ++e) {
      int k = kb + e;
      float v = (k < 200 && col < 30) ? Wz[k * 30 + col] : 0.f;
      uint32_t hi = bf16rne(v);
      float hf = __uint_as_float(hi << 16);
      uint32_t lo = bf16rne(v - hf);
      uint32_t bits = (hl == 0) ? hi : lo;
      out |= (bits & 0xFFFFu) << (16 * e);
    }
    wsu[OFF_WZSW + j] = out;
  } else if (i < 64512) {
    int j = i - 60416;
    int d = j & 3; int t = j >> 2;
    int lane = t & 63; t >>= 6;
    int ks = t & 7; int hl = t >> 3;
    int col = lane & 15;
    int kb = ks * 32 + (lane >> 4) * 8 + d * 2;
    uint32_t out = 0;
    for (int e = 0; e < 2; ++e) {
      int k = kb + e;
      float v = (col == 0 && k < 230) ? Wr[k] : 0.f;
      uint32_t hi = bf16rne(v);
      float hf = __uint_as_float(hi << 16);
      uint32_t lo = bf16rne(v - hf);
      uint32_t bits = (hl == 0) ? hi : lo;
      out |= (bits & 0xFFFFu) << (16 * e);
    }
    wsu[OFF_WRSW + j] = out;
  } else if (i < 66048) {
    ws[i] = 0.f;   // mean
  } else if (i < 67584) {
    ws[i] = 1.f;   // std
  }
}

// ---------------- actions = mean + std * normal(threefry) ----------------
__global__ __launch_bounds__(256) void k_actions(uint32_t k0, uint32_t k1, float* ws) {
  uint32_t idx = blockIdx.x * 256u + threadIdx.x;
  if (idx >= NELEM) return;
  uint32_t x0 = 0u, x1 = idx;
  tf2x32(k0, k1, x0, x1);
  float z = bits_to_normal(x0 ^ x1);
  uint32_t a = idx % 6u;  uint32_t q = idx / 6u;
  uint32_t c = q % 1000u; uint32_t q2 = q / 1000u;
  uint32_t b = q2 % 16u;  uint32_t t = q2 / 16u;
  uint32_t mi = (t * 16u + b) * 8u + a;
  float m = ws[OFF_MEAN + mi];
  float s = ws[OFF_STD + mi];
  ws[OFF_ACT + ((size_t)t * NROWS + b * 1000u + c) * 8u + a] = fmaf(s, z, m);
}

// ---------------- full 12-step rollout via split-bf16 MFMA ----------------
// 32 rows/block (2 M-tiles), 256 threads, 4 waves. Per-element MFMA chains
// IDENTICAL to the validated R7 kernel (absmax 0.0). vs R9: barriers now
// strictly separate every LDS read phase from every LDS write phase —
// NO read/write overlap of any kind (the suspected R8/R9 failure mode:
// a ds_write racing a ds_read_b128 beat whose other bytes carry nonzero
// MFMA weight).
//   phase order per t:
//   [B0] s1-reads |B1| h-writes |B2| s2-reads |B2b| s-writes |B3|
//        reward-reads |B4| act(t+1)-writes [B0]
__global__ __launch_bounds__(256) void k_roll(float* __restrict__ ws,
                                              const float* __restrict__ belief,
                                              const float* __restrict__ state,
                                              const float* __restrict__ bbp,
                                              const float* __restrict__ bzp,
                                              const float* __restrict__ brp) {
  __shared__ unsigned short xh[32 * 280];   // bf16 hi
  __shared__ unsigned short xl[32 * 280];   // bf16 lo

  const int tid = threadIdx.x;
  const int wv = tid >> 6;
  const int ln = tid & 63;
  const int r = ln & 15;
  const int kh = ln >> 4;
  const int grow0 = blockIdx.x * 32;
  const uint32_t* __restrict__ wsu = (const uint32_t*)ws;

  // stage-1 role (R7 mapping)
  const int NT  = (wv == 0) ? 4 : 3;
  const int ntb = (wv == 0) ? 0 : (1 + wv * 3);
  // stage-2 role
  const int m2 = wv & 1, j2 = wv >> 1;

  float bbv[4];
#pragma unroll
  for (int j = 0; j < 4; ++j) {
    int col = (ntb + j) * 16 + r;
    bbv[j] = (j < NT && col < 200) ? bbp[col] : 0.f;
  }
  float bzz;
  {
    int col = j2 * 16 + r;
    bzz = (col < 30) ? bzp[col] : 0.f;
  }
  const float br0 = brp[0];

  // init x: k<200 belief, 200..230 state, rest 0
  for (int idx = tid; idx < 32 * 256; idx += 256) {
    int row = idx >> 8, k = idx & 255;
    int b = (grow0 + row) / 1000;
    float v = 0.f;
    if (k < 200) v = belief[b * 200 + k];
    else if (k < 230) v = state[b * 30 + (k - 200)];
    uint32_t hi = bf16rne(v);
    float hf = __uint_as_float(hi << 16);
    uint32_t lo = bf16rne(v - hf);
    xh[row * 280 + k] = (unsigned short)hi;
    xl[row * 280 + k] = (unsigned short)lo;
  }
  __syncthreads();   // init zeros complete before t=0 action writes (WAW fence)

  // t=0 actions
  {
    const float* actp = ws + OFF_ACT + ((size_t)0 * NROWS + grow0) * 8;
    if (tid < 192) {
      int row = tid / 6, a = tid - row * 6;
      float v = actp[row * 8 + a];
      uint32_t hi = bf16rne(v);
      float hf = __uint_as_float(hi << 16);
      uint32_t lo = bf16rne(v - hf);
      xh[row * 280 + 230 + a] = (unsigned short)hi;
      xl[row * 280 + 230 + a] = (unsigned short)lo;
    }
  }
  __syncthreads();                           // B0(t=0)

  f32x4 racc = {0.f, 0.f, 0.f, 0.f};

#pragma unroll 1
  for (int t = 0; t < TT; ++t) {
    // ---- stage 1: h = tanh(x @ W_all + bb); 2 M-tiles x NT N-tiles ----
    f32x4 acc[2][4];
#pragma unroll
    for (int m = 0; m < 2; ++m)
#pragma unroll
      for (int j = 0; j < 4; ++j) {
        f32x4 c = {bbv[j], bbv[j], bbv[j], bbv[j]};
        acc[m][j] = c;
      }

#pragma unroll 2
    for (int ks = 0; ks < 8; ++ks) {
      short8v Ah[2], Al[2];
      const int kbase = ks * 32 + kh * 8;
#pragma unroll
      for (int m = 0; m < 2; ++m) {
        int off = (m * 16 + r) * 280 + kbase;
        Ah[m] = *(const short8v*)&xh[off];
        Al[m] = *(const short8v*)&xl[off];
      }
#pragma unroll
      for (int j = 0; j < 4; ++j) {
        if (j < NT) {
          const int nt = ntb + j;
          const short8v Bh = *(const short8v*)(wsu + OFF_WSW + (((0 * 13 + nt) * 8 + ks) * 64 + ln) * 4);
          const short8v Bl = *(const short8v*)(wsu + OFF_WSW + (((1 * 13 + nt) * 8 + ks) * 64 + ln) * 4);
#pragma unroll
          for (int m = 0; m < 2; ++m) {
            f32x4 c = acc[m][j];
            c = __builtin_amdgcn_mfma_f32_16x16x32_bf16(Al[m], Bl, c, 0, 0, 0);
            c = __builtin_amdgcn_mfma_f32_16x16x32_bf16(Ah[m], Bl, c, 0, 0, 0);
            c = __builtin_amdgcn_mfma_f32_16x16x32_bf16(Al[m], Bh, c, 0, 0, 0);
            c = __builtin_amdgcn_mfma_f32_16x16x32_bf16(Ah[m], Bh, c, 0, 0, 0);
            acc[m][j] = c;
          }
        }
      }
    }
    __syncthreads();                           // B1: all s1 reads done

    // h epilogue: tanh, split, write back (D: row=(ln>>4)*4+reg, col=ln&15)
#pragma unroll
    for (int j = 0; j < 4; ++j) {
      int col = (ntb + j) * 16 + r;
      if (j < NT && col < 200) {
#pragma unroll
        for (int m = 0; m < 2; ++m) {
#pragma unroll
          for (int reg = 0; reg < 4; ++reg) {
            int row = m * 16 + kh * 4 + reg;
            float h = tanhf(acc[m][j][reg]);
            uint32_t hi = bf16rne(h);
            float hf = __uint_as_float(hi << 16);
            uint32_t lo = bf16rne(h - hf);
            xh[row * 280 + col] = (unsigned short)hi;
            xl[row * 280 + col] = (unsigned short)lo;
          }
        }
      }
    }
    __syncthreads();                           // B2: h writes complete

    // ---- stage 2: s = tanh(h @ Wz + bz); unit (m2, j2) — reads only ----
    f32x4 acc2 = {bzz, bzz, bzz, bzz};
#pragma unroll
    for (int ks = 0; ks < 7; ++ks) {          // K=224; k>=200 x Wz==0 benign
      int off = (m2 * 16 + r) * 280 + ks * 32 + kh * 8;
      short8v Ah2 = *(const short8v*)&xh[off];
      short8v Al2 = *(const short8v*)&xl[off];
      const short8v Bh = *(const short8v*)(wsu + OFF_WZSW + (((0 * 2 + j2) * 7 + ks) * 64 + ln) * 4);
      const short8v Bl = *(const short8v*)(wsu + OFF_WZSW + (((1 * 2 + j2) * 7 + ks) * 64 + ln) * 4);
      acc2 = __builtin_amdgcn_mfma_f32_16x16x32_bf16(Al2, Bl, acc2, 0, 0, 0);
      acc2 = __builtin_amdgcn_mfma_f32_16x16x32_bf16(Ah2, Bl, acc2, 0, 0, 0);
      acc2 = __builtin_amdgcn_mfma_f32_16x16x32_bf16(Al2, Bh, acc2, 0, 0, 0);
      acc2 = __builtin_amdgcn_mfma_f32_16x16x32_bf16(Ah2, Bh, acc2, 0, 0, 0);
    }
    __syncthreads();                           // B2b: all s2 reads done

    // s epilogue: write k 200..230 of M-tile m2, col-tile j2
    {
      int col = j2 * 16 + r;
      if (col < 30) {
#pragma unroll
        for (int reg = 0; reg < 4; ++reg) {
          int row = m2 * 16 + kh * 4 + reg;
          float s = tanhf(acc2[reg]);
          uint32_t hi = bf16rne(s);
          float hf = __uint_as_float(hi << 16);
          uint32_t lo = bf16rne(s - hf);
          xh[row * 280 + 200 + col] = (unsigned short)hi;
          xl[row * 280 + 200 + col] = (unsigned short)lo;
        }
      }
    }
    __syncthreads();                           // B3: s writes complete

    // ---- reward: racc += [h|s] @ Wr' (col 0); waves 0,1 full chain ----
    if (wv < 2) {
#pragma unroll
      for (int ks = 0; ks < 8; ++ks) {
        int off = (wv * 16 + r) * 280 + ks * 32 + kh * 8;
        short8v Ah3 = *(const short8v*)&xh[off];
        short8v Al3 = *(const short8v*)&xl[off];
        const short8v Bh = *(const short8v*)(wsu + OFF_WRSW + ((0 * 8 + ks) * 64 + ln) * 4);
        const short8v Bl = *(const short8v*)(wsu + OFF_WRSW + ((1 * 8 + ks) * 64 + ln) * 4);
        racc = __builtin_amdgcn_mfma_f32_16x16x32_bf16(Al3, Bl, racc, 0, 0, 0);
        racc = __builtin_amdgcn_mfma_f32_16x16x32_bf16(Ah3, Bl, racc, 0, 0, 0);
        racc = __builtin_amdgcn_mfma_f32_16x16x32_bf16(Al3, Bh, racc, 0, 0, 0);
        racc = __builtin_amdgcn_mfma_f32_16x16x32_bf16(Ah3, Bh, racc, 0, 0, 0);
      }
    }
    __syncthreads();                           // B4: all reward reads done

    // ---- actions for t+1 (writes only; next loop head has no reads before B0)
    if (t + 1 < TT) {
      const float* actp = ws + OFF_ACT + ((size_t)(t + 1) * NROWS + grow0) * 8;
      if (tid < 192) {
        int row = tid / 6, a = tid - row * 6;
        float v = actp[row * 8 + a];
        uint32_t hi = bf16rne(v);
        float hf = __uint_as_float(hi << 16);
        uint32_t lo = bf16rne(v - hf);
        xh[row * 280 + 230 + a] = (unsigned short)hi;
        xl[row * 280 + 230 + a] = (unsigned short)lo;
      }
      __syncthreads();                         // B0(t+1): action writes complete
    }
  }

  if (wv < 2 && r == 0) {
#pragma unroll
    for (int reg = 0; reg < 4; ++reg) {
      int row = wv * 16 + kh * 4 + reg;
      ws[OFF_RET + grow0 + row] = racc[reg] + 12.0f * br0;
    }
  }
}

// ---------------- top-k via full bitonic sort (desc, ties by index) ----------------
__global__ __launch_bounds__(1024) void k_topk(float* ws) {
  __shared__ float sv[1024];
  __shared__ int si[1024];
  const int b = blockIdx.x, tid = threadIdx.x;
  const float* ret = ws + OFF_RET + b * 1000;
  sv[tid] = (tid < 1000) ? ret[tid] : -3.0e38f;
  si[tid] = tid;
  __syncthreads();
  for (int k = 2; k <= 1024; k <<= 1) {
    for (int j = k >> 1; j > 0; j >>= 1) {
      int ixj = tid ^ j;
      if (ixj > tid) {
        float v1 = sv[tid], v2 = sv[ixj];
        int i1 = si[tid], i2 = si[ixj];
        bool gt = (v1 < v2) || (v1 == v2 && i1 > i2);
        bool up = ((tid & k) == 0);
        if (up ? gt : !gt) {
          sv[tid] = v2; sv[ixj] = v1;
          si[tid] = i2; si[ixj] = i1;
        }
      }
      __syncthreads();
    }
  }
  int* topk = (int*)(ws + OFF_TOPK);
  if (tid < 100) topk[b * 100 + tid] = si[tid];
}

// ---------------- mean/std over elites: one wave per (t,b,a) ----------------
__global__ __launch_bounds__(256) void k_meanstd(float* ws) {
  const int g = blockIdx.x * 4 + (threadIdx.x >> 6);  // 0..1151
  const int ln = threadIdx.x & 63;
  const int t = g / 96; const int rem = g - t * 96;
  const int b = rem / 6; const int a = rem - b * 6;
  const int* topk = (const int*)(ws + OFF_TOPK) + b * 100;
  const float* act = ws + OFF_ACT + (size_t)t * NROWS * 8;
  const bool h2 = (ln < 36);
  int c1 = topk[ln];
  float x1 = act[((size_t)b * 1000 + c1) * 8 + a];
  float x2 = 0.f;
  if (h2) { int cc = topk[ln + 64]; x2 = act[((size_t)b * 1000 + cc) * 8 + a]; }
  float s = x1 + x2;
#pragma unroll
  for (int m = 1; m < 64; m <<= 1) s += __shfl_xor(s, m, 64);
  const float mean = s / 100.0f;
  float d = x1 - mean; float qq = d * d;
  if (h2) { float d2 = x2 - mean; qq += d2 * d2; }
#pragma unroll
  for (int m = 1; m < 64; m <<= 1) qq += __shfl_xor(qq, m, 64);
  if (ln == 0) {
    ws[OFF_MEAN + ((size_t)t * 16 + b) * 8 + a] = mean;
    ws[OFF_STD  + ((size_t)t * 16 + b) * 8 + a] = sqrtf(qq / 100.0f);
  }
}

__global__ void k_out(const float* ws, float* out) {
  int i = threadIdx.x;
  if (i < 96) out[i] = ws[OFF_MEAN + (i / 6) * 8 + (i % 6)];
}

extern "C" void kernel_launch(void* const* d_in, const int* in_sizes, int n_in,
                              void* d_out, int out_size, void* d_ws, size_t ws_size,
                              hipStream_t stream) {
  const float* belief = (const float*)d_in[0];
  const float* state  = (const float*)d_in[1];
  const float* Wb  = (const float*)d_in[2];
  const float* Ws_ = (const float*)d_in[3];
  const float* Wa  = (const float*)d_in[4];
  const float* bb  = (const float*)d_in[5];
  const float* Wz  = (const float*)d_in[6];
  const float* bz  = (const float*)d_in[7];
  const float* Wr  = (const float*)d_in[8];
  const float* br  = (const float*)d_in[9];
  float* ws = (float*)d_ws;   // needs ~6.5 MB

  k_prep<<<264, 256, 0, stream>>>(Wb, Ws_, Wa, Wz, Wr, ws);

  for (int it = 0; it < NITERS; ++it) {
    uint32_t f0 = 0u, f1 = (uint32_t)it;
    tf2x32(0u, 42u, f0, f1);
    k_actions<<<4500, 256, 0, stream>>>(f0, f1, ws);
    k_roll<<<500, 256, 0, stream>>>(ws, belief, state, bb, bz, br);
    k_topk<<<16, 1024, 0, stream>>>(ws);
    k_meanstd<<<288, 256, 0, stream>>>(ws);
  }
  k_out<<<1, 128, 0, stream>>>(ws, (float*)d_out);
}